// Round 7
// baseline (1241.554 us; speedup 1.0000x reference)
//
#include <hip/hip_runtime.h>
#include <hip/hip_bf16.h>
#include <math.h>

typedef unsigned short u16;
typedef __attribute__((ext_vector_type(8))) short bf16x8;
typedef __attribute__((ext_vector_type(4))) float f32x4;
typedef __attribute__((address_space(1))) unsigned int gu32;
typedef __attribute__((address_space(3))) unsigned int lu32;

#define DD 1024
#define PP 32

__device__ __forceinline__ u16 f2bf(float f) {
  unsigned u = __float_as_uint(f);
  unsigned r = u + 0x7fffu + ((u >> 16) & 1u);
  return (u16)(r >> 16);
}
__device__ __forceinline__ float bf2f(u16 h) {
  return __uint_as_float(((unsigned)h) << 16);
}

// ---------------- conversions ----------------
__global__ __launch_bounds__(256) void k_convert_x(const float* __restrict__ x,
                                                   u16* __restrict__ comb, int n4) {
  for (int i = blockIdx.x * 256 + threadIdx.x; i < n4; i += gridDim.x * 256) {
    float4 v = ((const float4*)x)[i];
    int row = i >> 8;
    int c4  = i & 255;
    ushort4 o;
    o.x = f2bf(v.x); o.y = f2bf(v.y); o.z = f2bf(v.z); o.w = f2bf(v.w);
    *(ushort4*)(comb + ((size_t)row << 11) + (c4 << 2)) = o;
  }
}

__global__ __launch_bounds__(256) void k_convert(const float* __restrict__ in,
                                                 u16* __restrict__ out, int n4) {
  for (int i = blockIdx.x * 256 + threadIdx.x; i < n4; i += gridDim.x * 256) {
    float4 v = ((const float4*)in)[i];
    ushort4 o;
    o.x = f2bf(v.x); o.y = f2bf(v.y); o.z = f2bf(v.z); o.w = f2bf(v.w);
    ((ushort4*)out)[i] = o;
  }
}

__global__ __launch_bounds__(256) void k_proto_prep(const float* __restrict__ protos,
                                                    u16* __restrict__ pb) {
  __shared__ float sb[4];
  int row = blockIdx.x, tid = threadIdx.x;
  float4 v = ((const float4*)(protos + row * DD))[tid];
  float q = v.x * v.x + v.y * v.y + v.z * v.z + v.w * v.w;
#pragma unroll
  for (int off = 32; off; off >>= 1) q += __shfl_xor(q, off);
  if ((tid & 63) == 0) sb[tid >> 6] = q;
  __syncthreads();
  q = sb[0] + sb[1] + sb[2] + sb[3];
  float inv = 1.0f / fmaxf(sqrtf(q), 1e-12f);
  ushort4 o;
  o.x = f2bf(v.x * inv); o.y = f2bf(v.y * inv); o.z = f2bf(v.z * inv); o.w = f2bf(v.w * inv);
  ((ushort4*)(pb + row * DD))[tid] = o;
}

__global__ __launch_bounds__(256) void k_protoT(const float* __restrict__ protos,
                                                u16* __restrict__ pbT) {
  int i = blockIdx.x * 256 + threadIdx.x;
  if (i < DD * PP) {
    int p = i & 31, d = i >> 5;
    pbT[i] = f2bf(protos[p * DD + d]);
  }
}

// ---------------- 128x128 bf16 GEMM, A via LDS (dbuf, swizzled), B via L2->regs ----------
// C[m,n] = sum_k A[m,k] * Bm[n,k].  4 waves (2x2) of 64x64; 3 blocks/CU.
// Per K-tile (BK=64): 2 phases, 2 barriers, counted vmcnt (never 0 mid-loop).
#define GLL(gsrc, ldst) __builtin_amdgcn_global_load_lds((gu32*)(gsrc), (lu32*)(ldst), 16, 0, 0)

template <int EPI>
__global__ __launch_bounds__(256, 3) void k_gemm8(const u16* __restrict__ A, int lda,
                                                  const u16* __restrict__ Bm,
                                                  const float* __restrict__ bias,
                                                  const u16* __restrict__ residb,
                                                  void* __restrict__ Cout, int ldc,
                                                  int K, int nbn) {
  __shared__ u16 Als[2][128 * 64];
  const int tid = threadIdx.x;
  const int wid = tid >> 6, lane = tid & 63;
  const int wm = wid >> 1, wn = wid & 1;
  const int lm = lane & 15, lk = lane >> 4;
  const int NT = K >> 6;

  const int scol_sw = (((lane & 7) ^ ((lane >> 3) & 7)) << 3);  // u16 units
  const int srow = lane >> 3;

  // XCD chunked swizzle: 8 bn-blocks sharing an A-panel run back-to-back on one XCD
  int g = blockIdx.x;
  int cpx = gridDim.x >> 3;
  int lin = (g & 7) * cpx + (g >> 3);
  int bn = lin % nbn, bm = lin / nbn;
  const size_t bmBase = (size_t)bm * 128;
  const size_t bnBase = (size_t)bn * 128;

  f32x4 acc[4][4];
#pragma unroll
  for (int i = 0; i < 4; ++i)
#pragma unroll
    for (int j = 0; j < 4; ++j) acc[i][j] = (f32x4){0.f, 0.f, 0.f, 0.f};

  bf16x8 a[2][2], b[4][2];

  // B base for this wave: row (bnBase + wn*64 + lm), fragments at +ni*16 rows
  const u16* Bg = Bm + (bnBase + wn * 64 + lm) * (size_t)K + lk * 8;

  // stage one 4KB A-line (32 rows): line j covers rows [j*32, j*32+32)
#define STAGE_L(bufv, kt, j) do {                                               \
    GLL(A + (bmBase + (j) * 32 + wid * 8 + srow) * lda + scol_sw + (kt) * 64,   \
        &Als[bufv][((j) * 32 + wid * 8) * 64]);                                 \
  } while (0)

  // ds_read a-frags for mh half (frag rows mh*2 .. mh*2+1)
#define LOAD_A(bufv, mh) do {                                                   \
    _Pragma("unroll") for (int mi2 = 0; mi2 < 2; ++mi2) {                       \
      int row = wm * 64 + ((mh) * 2 + mi2) * 16 + lm;                           \
      _Pragma("unroll") for (int kk = 0; kk < 2; ++kk)                          \
        a[mi2][kk] = *(const bf16x8*)&Als[bufv][row * 64 + ((kk * 32 + lk * 8) ^ ((lm & 7) << 3))]; \
    }                                                                           \
  } while (0)

#define LOAD_B(kt) do {                                                         \
    _Pragma("unroll") for (int ni2 = 0; ni2 < 4; ++ni2)                         \
    _Pragma("unroll") for (int kk = 0; kk < 2; ++kk)                            \
      b[ni2][kk] = *(const bf16x8*)(Bg + (size_t)(ni2 * 16) * K + (kt) * 64 + kk * 32); \
  } while (0)

#define BARRIER do { __builtin_amdgcn_s_barrier(); asm volatile("" ::: "memory"); } while (0)

#define MFMA_H(mh) do {                                                         \
    __builtin_amdgcn_s_setprio(1);                                              \
    _Pragma("unroll") for (int mi2 = 0; mi2 < 2; ++mi2)                         \
    _Pragma("unroll") for (int ni2 = 0; ni2 < 4; ++ni2)                         \
    _Pragma("unroll") for (int kk = 0; kk < 2; ++kk)                            \
      acc[(mh) * 2 + mi2][ni2] = __builtin_amdgcn_mfma_f32_16x16x32_bf16(       \
          a[mi2][kk], b[ni2][kk], acc[(mh) * 2 + mi2][ni2], 0, 0, 0);           \
    __builtin_amdgcn_s_setprio(0);                                              \
  } while (0)

  // prologue: stage tile0 lines in order l0,l2,l1,l3 (P1 of tile0 needs l0,l2)
  STAGE_L(0, 0, 0); STAGE_L(0, 0, 2); STAGE_L(0, 0, 1); STAGE_L(0, 0, 3);

  // per-tile: P1 {vmcnt(2); bar; load B(T); ds_read mh0; stage l0,l2(T+1); mfma mh0}
  //           P2 {vmcnt(10|8); bar; ds_read mh1; stage l1,l3(T+1); mfma mh1}
#define TILE(T, P) do {                                                         \
    asm volatile("s_waitcnt vmcnt(2)" ::: "memory");                            \
    BARRIER;                                                                    \
    LOAD_B(T);                                                                  \
    LOAD_A(P, 0);                                                               \
    if ((T) + 1 < NT) { STAGE_L((P) ^ 1, (T) + 1, 0); STAGE_L((P) ^ 1, (T) + 1, 2); } \
    MFMA_H(0);                                                                  \
    if ((T) + 1 < NT) asm volatile("s_waitcnt vmcnt(10)" ::: "memory");         \
    else               asm volatile("s_waitcnt vmcnt(8)" ::: "memory");         \
    BARRIER;                                                                    \
    LOAD_A(P, 1);                                                               \
    if ((T) + 1 < NT) { STAGE_L((P) ^ 1, (T) + 1, 1); STAGE_L((P) ^ 1, (T) + 1, 3); } \
    MFMA_H(1);                                                                  \
  } while (0)

  for (int T = 0; T < NT; T += 2) {
    TILE(T, 0);
    TILE(T + 1, 1);
  }

  // epilogue: C/D layout col = lane&15 (n), row = (lane>>4)*4 + r (m)
  const int rbase = lk * 4;
  const size_t gr0 = bmBase + wm * 64;
  const int gc0 = (int)bnBase + wn * 64;
#pragma unroll
  for (int mi = 0; mi < 4; ++mi) {
#pragma unroll
    for (int ni = 0; ni < 4; ++ni) {
      int gcol = gc0 + ni * 16 + lm;
      float bv = bias[gcol];
#pragma unroll
      for (int r = 0; r < 4; ++r) {
        size_t grow = gr0 + mi * 16 + rbase + r;
        float v = acc[mi][ni][r] + bv;
        if (EPI == 0) {
          ((u16*)Cout)[grow * ldc + gcol] = f2bf(v);
        } else {
          float gl = 0.5f * v * (1.0f + erff(v * 0.70710678118654752f));
          float y = gl + bf2f(residb[grow * 2048 + gcol]);
          ((float*)Cout)[grow * ldc + gcol] = y;
        }
      }
    }
  }
#undef STAGE_L
#undef LOAD_A
#undef LOAD_B
#undef MFMA_H
#undef TILE
#undef BARRIER
}

// ---------------- fused: sim (MFMA) -> softmax -> retrieved (MFMA) ----------------
__global__ __launch_bounds__(256) void k_mid(const u16* __restrict__ h,
                                             const u16* __restrict__ pb,
                                             const u16* __restrict__ pbT,
                                             u16* __restrict__ comb) {
  __shared__ u16 attn_sm[4][16 * 32];
  const int tid = threadIdx.x;
  const int w = tid >> 6, lane = tid & 63;
  const int lm = lane & 15, lk = lane >> 4;
  const int row0 = blockIdx.x * 64 + w * 16;

  f32x4 zero = {0.f, 0.f, 0.f, 0.f};
  f32x4 acc0 = zero, acc1 = zero;
  float ss = 0.f;

  const u16* hrow = h + ((size_t)(row0 + lm) << 10) + lk * 8;
  const u16* pb0 = pb + (size_t)lm * DD + lk * 8;
  const u16* pb1 = pb + (size_t)(16 + lm) * DD + lk * 8;
#pragma unroll 4
  for (int k0 = 0; k0 < DD; k0 += 32) {
    bf16x8 af = *(const bf16x8*)(hrow + k0);
    bf16x8 b0 = *(const bf16x8*)(pb0 + k0);
    bf16x8 b1 = *(const bf16x8*)(pb1 + k0);
    acc0 = __builtin_amdgcn_mfma_f32_16x16x32_bf16(af, b0, acc0, 0, 0, 0);
    acc1 = __builtin_amdgcn_mfma_f32_16x16x32_bf16(af, b1, acc1, 0, 0, 0);
#pragma unroll
    for (int j = 0; j < 8; ++j) {
      float hv = bf2f((u16)af[j]);
      ss += hv * hv;
    }
  }
  ss += __shfl_xor(ss, 16);
  ss += __shfl_xor(ss, 32);
  float inv = 10.0f / fmaxf(sqrtf(ss), 1e-12f);

  float a0[4], a1[4];
#pragma unroll
  for (int r = 0; r < 4; ++r) {
    float invr = __shfl(inv, lk * 4 + r);
    float s0 = acc0[r] * invr;
    float s1 = acc1[r] * invr;
    float mr = fmaxf(s0, s1);
#pragma unroll
    for (int off = 1; off < 16; off <<= 1) mr = fmaxf(mr, __shfl_xor(mr, off));
    float e0 = expf(s0 - mr);
    float e1 = expf(s1 - mr);
    float sum = e0 + e1;
#pragma unroll
    for (int off = 1; off < 16; off <<= 1) sum += __shfl_xor(sum, off);
    float rs = 1.0f / sum;
    a0[r] = e0 * rs;
    a1[r] = e1 * rs;
  }

  u16* as = attn_sm[w];
#pragma unroll
  for (int r = 0; r < 4; ++r) {
    as[(lk * 4 + r) * 32 + lm] = f2bf(a0[r]);
    as[(lk * 4 + r) * 32 + 16 + lm] = f2bf(a1[r]);
  }
  __syncthreads();
  bf16x8 battn = *(const bf16x8*)(as + lm * 32 + lk * 8);

  u16* crow = comb + ((size_t)(row0 + lm) << 11) + DD;
#pragma unroll 4
  for (int d0 = 0; d0 < DD; d0 += 16) {
    bf16x8 ap = *(const bf16x8*)(pbT + (size_t)(d0 + lm) * PP + lk * 8);
    f32x4 rc = __builtin_amdgcn_mfma_f32_16x16x32_bf16(ap, battn, zero, 0, 0, 0);
    ushort4 o;
    o.x = f2bf(rc[0]); o.y = f2bf(rc[1]); o.z = f2bf(rc[2]); o.w = f2bf(rc[3]);
    *(ushort4*)(crow + d0 + lk * 4) = o;
  }
}

// ---------------- in-place LayerNorm over rows of 1024 ----------------
__global__ __launch_bounds__(256) void k_ln(float* __restrict__ io,
                                            const float* __restrict__ gamma,
                                            const float* __restrict__ beta) {
  __shared__ float sb[8];
  size_t row = blockIdx.x;
  float4* rp = (float4*)(io + (row << 10));
  int tid = threadIdx.x;
  float4 v = rp[tid];
  float s = v.x + v.y + v.z + v.w;
  float q = v.x * v.x + v.y * v.y + v.z * v.z + v.w * v.w;
#pragma unroll
  for (int off = 32; off; off >>= 1) { s += __shfl_xor(s, off); q += __shfl_xor(q, off); }
  if ((tid & 63) == 0) { sb[tid >> 6] = s; sb[4 + (tid >> 6)] = q; }
  __syncthreads();
  s = sb[0] + sb[1] + sb[2] + sb[3];
  q = sb[4] + sb[5] + sb[6] + sb[7];
  float mu = s * (1.f / 1024.f);
  float var = q * (1.f / 1024.f) - mu * mu;
  float rstd = rsqrtf(var + 1e-5f);
  float4 g = ((const float4*)gamma)[tid];
  float4 b = ((const float4*)beta)[tid];
  v.x = (v.x - mu) * rstd * g.x + b.x;
  v.y = (v.y - mu) * rstd * g.y + b.y;
  v.z = (v.z - mu) * rstd * g.z + b.z;
  v.w = (v.w - mu) * rstd * g.w + b.w;
  rp[tid] = v;
}

extern "C" void kernel_launch(void* const* d_in, const int* in_sizes, int n_in,
                              void* d_out, int out_size, void* d_ws, size_t ws_size,
                              hipStream_t stream) {
  const float* x      = (const float*)d_in[0];
  const float* Wi     = (const float*)d_in[1];
  const float* bi     = (const float*)d_in[2];
  const float* Wo     = (const float*)d_in[3];
  const float* bo     = (const float*)d_in[4];
  const float* gamma  = (const float*)d_in[5];
  const float* beta   = (const float*)d_in[6];
  const float* protos = (const float*)d_in[7];
  const int Brows = in_sizes[0] / DD;  // 65536

  u16* comb = (u16*)d_ws;                        // [B, 2048] bf16
  u16* WiB  = comb + (size_t)Brows * 2048;       // [1024, 1024]
  u16* WoB  = WiB + (size_t)1024 * 1024;         // [1024, 2048]
  u16* pb   = WoB + (size_t)1024 * 2048;         // [32, 1024] normalized
  u16* pbT  = pb + (size_t)PP * DD;              // [1024, 32] raw transposed
  u16* hbuf = (u16*)d_out;                       // h bf16 lives in d_out storage

  k_convert_x<<<4096, 256, 0, stream>>>(x, comb, Brows * 256);
  k_convert<<<1024, 256, 0, stream>>>(Wi, WiB, 1024 * 1024 / 4);
  k_convert<<<2048, 256, 0, stream>>>(Wo, WoB, 1024 * 2048 / 4);
  k_proto_prep<<<PP, 256, 0, stream>>>(protos, pb);
  k_protoT<<<(DD * PP + 255) / 256, 256, 0, stream>>>(protos, pbT);

  const int nbn = 1024 / 128;                    // 8 col-blocks
  const int nwg = nbn * (Brows / 128);           // 4096 blocks

  // h = x @ Wi^T + bi
  k_gemm8<0><<<nwg, 256, 0, stream>>>(comb, 2048, WiB, bi, nullptr,
                                      (void*)hbuf, DD, DD, nbn);
  // fused sim -> softmax -> retrieved into combined right half
  k_mid<<<Brows / 64, 256, 0, stream>>>(hbuf, pb, pbT, comb);
  // y = gelu(combined @ Wo^T + bo) + bf16(x)  -> d_out (f32)
  k_gemm8<1><<<nwg, 256, 0, stream>>>(comb, 2048, WoB, bo, comb,
                                      d_out, DD, 2 * DD, nbn);
  // in-place LayerNorm
  k_ln<<<Brows, 256, 0, stream>>>((float*)d_out, gamma, beta);
}

// Round 8
// 880.192 us; speedup vs baseline: 1.4105x; 1.4105x over previous
//
#include <hip/hip_runtime.h>
#include <hip/hip_bf16.h>
#include <math.h>

typedef unsigned short u16;
typedef __attribute__((ext_vector_type(8))) short bf16x8;
typedef __attribute__((ext_vector_type(4))) float f32x4;
typedef __attribute__((address_space(1))) unsigned int gu32;
typedef __attribute__((address_space(3))) unsigned int lu32;

#define DD 1024
#define PP 32

__device__ __forceinline__ u16 f2bf(float f) {
  unsigned u = __float_as_uint(f);
  unsigned r = u + 0x7fffu + ((u >> 16) & 1u);
  return (u16)(r >> 16);
}
__device__ __forceinline__ float bf2f(u16 h) {
  return __uint_as_float(((unsigned)h) << 16);
}

// ---------------- conversions ----------------
__global__ __launch_bounds__(256) void k_convert_x(const float* __restrict__ x,
                                                   u16* __restrict__ comb, int n4) {
  for (int i = blockIdx.x * 256 + threadIdx.x; i < n4; i += gridDim.x * 256) {
    float4 v = ((const float4*)x)[i];
    int row = i >> 8;
    int c4  = i & 255;
    ushort4 o;
    o.x = f2bf(v.x); o.y = f2bf(v.y); o.z = f2bf(v.z); o.w = f2bf(v.w);
    *(ushort4*)(comb + ((size_t)row << 11) + (c4 << 2)) = o;
  }
}

__global__ __launch_bounds__(256) void k_convert(const float* __restrict__ in,
                                                 u16* __restrict__ out, int n4) {
  for (int i = blockIdx.x * 256 + threadIdx.x; i < n4; i += gridDim.x * 256) {
    float4 v = ((const float4*)in)[i];
    ushort4 o;
    o.x = f2bf(v.x); o.y = f2bf(v.y); o.z = f2bf(v.z); o.w = f2bf(v.w);
    ((ushort4*)out)[i] = o;
  }
}

__global__ __launch_bounds__(256) void k_proto_prep(const float* __restrict__ protos,
                                                    u16* __restrict__ pb) {
  __shared__ float sb[4];
  int row = blockIdx.x, tid = threadIdx.x;
  float4 v = ((const float4*)(protos + row * DD))[tid];
  float q = v.x * v.x + v.y * v.y + v.z * v.z + v.w * v.w;
#pragma unroll
  for (int off = 32; off; off >>= 1) q += __shfl_xor(q, off);
  if ((tid & 63) == 0) sb[tid >> 6] = q;
  __syncthreads();
  q = sb[0] + sb[1] + sb[2] + sb[3];
  float inv = 1.0f / fmaxf(sqrtf(q), 1e-12f);
  ushort4 o;
  o.x = f2bf(v.x * inv); o.y = f2bf(v.y * inv); o.z = f2bf(v.z * inv); o.w = f2bf(v.w * inv);
  ((ushort4*)(pb + row * DD))[tid] = o;
}

__global__ __launch_bounds__(256) void k_protoT(const float* __restrict__ protos,
                                                u16* __restrict__ pbT) {
  int i = blockIdx.x * 256 + threadIdx.x;
  if (i < DD * PP) {
    int p = i & 31, d = i >> 5;
    pbT[i] = f2bf(protos[p * DD + d]);
  }
}

// ---------------- 256x256 bf16 GEMM (B^T layout), T2 swizzle, merged sync ----------------
// One barrier + one vmcnt(0) per K-tile. Body T stages tile T+1 entirely into buf^1
// (disjoint from all reads of buf p this body), then 4 ds-read/MFMA quadrants with
// no interior syncs (compiler emits fine-grained lgkmcnt).
#define GLL(gsrc, ldst) __builtin_amdgcn_global_load_lds((gu32*)(gsrc), (lu32*)(ldst), 16, 0, 0)

template <int EPI>
__global__ __launch_bounds__(512, 2) void k_gemm8(const u16* __restrict__ A, int lda,
                                                  const u16* __restrict__ Bm,
                                                  const float* __restrict__ bias,
                                                  const u16* __restrict__ residb,
                                                  void* __restrict__ Cout, int ldc,
                                                  int K, int nbn) {
  __shared__ u16 Als[2][256 * 64];
  __shared__ u16 Bls[2][256 * 64];
  const int tid = threadIdx.x;
  const int wid = tid >> 6, lane = tid & 63;
  const int wm = wid >> 2, wn = wid & 3;
  const int lm = lane & 15, lk = lane >> 4;
  const int NT = K >> 6;

  const int scol_sw = (((lane & 7) ^ ((lane >> 3) & 7)) << 3);
  const int srow = lane >> 3;

  // XCD chunked swizzle
  int g = blockIdx.x;
  int cpx = gridDim.x >> 3;
  int lin = (g & 7) * cpx + (g >> 3);
  int bn = lin % nbn, bm = lin / nbn;
  const size_t bmBase = (size_t)bm * 256;
  const size_t bnBase = (size_t)bn * 256;

  f32x4 acc[8][4];
#pragma unroll
  for (int i = 0; i < 8; ++i)
#pragma unroll
    for (int j = 0; j < 4; ++j) acc[i][j] = (f32x4){0.f, 0.f, 0.f, 0.f};

  bf16x8 a[4][2], b0[2][2], b1[2][2];

#define STAGE_A(bufv, kt, mh) do {                                              \
    int arow = (mh) * 64 + wid * 8 + srow;                                      \
    int acol = scol_sw + (kt) * 64;                                             \
    GLL(A + (bmBase + arow) * lda + acol, &Als[bufv][((mh) * 64 + wid * 8) * 64]);       \
    GLL(A + (bmBase + 128 + arow) * lda + acol, &Als[bufv][(128 + (mh) * 64 + wid * 8) * 64]); \
  } while (0)

#define STAGE_B(bufv, kt, nh) do {                                              \
    int br0 = ((wid >> 2) << 6) + (nh) * 32 + ((wid & 3) << 3);                 \
    int bcol = scol_sw + (kt) * 64;                                             \
    GLL(Bm + (bnBase + br0 + srow) * (size_t)K + bcol, &Bls[bufv][br0 * 64]);       \
    GLL(Bm + (bnBase + 128 + br0 + srow) * (size_t)K + bcol, &Bls[bufv][(128 + br0) * 64]); \
  } while (0)

#define LOAD_A(bufv, mh) do {                                                   \
    _Pragma("unroll") for (int mi2 = 0; mi2 < 4; ++mi2) {                       \
      int row = wm * 128 + (mh) * 64 + mi2 * 16 + lm;                           \
      _Pragma("unroll") for (int kk = 0; kk < 2; ++kk)                          \
        a[mi2][kk] = *(const bf16x8*)&Als[bufv][row * 64 + ((kk * 32 + lk * 8) ^ ((lm & 7) << 3))]; \
    }                                                                           \
  } while (0)

#define LOAD_B(dst, bufv, nh) do {                                              \
    _Pragma("unroll") for (int ni2 = 0; ni2 < 2; ++ni2) {                       \
      int row = wn * 64 + (nh) * 32 + ni2 * 16 + lm;                            \
      _Pragma("unroll") for (int kk = 0; kk < 2; ++kk)                          \
        dst[ni2][kk] = *(const bf16x8*)&Bls[bufv][row * 64 + ((kk * 32 + lk * 8) ^ ((lm & 7) << 3))]; \
    }                                                                           \
  } while (0)

#define BARRIER do { __builtin_amdgcn_s_barrier(); asm volatile("" ::: "memory"); } while (0)

#define MFMA_Q(bb, mh, nh) do {                                                 \
    __builtin_amdgcn_s_setprio(1);                                              \
    _Pragma("unroll") for (int mi2 = 0; mi2 < 4; ++mi2)                         \
    _Pragma("unroll") for (int ni2 = 0; ni2 < 2; ++ni2)                         \
    _Pragma("unroll") for (int kk = 0; kk < 2; ++kk)                            \
      acc[(mh) * 4 + mi2][(nh) * 2 + ni2] = __builtin_amdgcn_mfma_f32_16x16x32_bf16( \
          a[mi2][kk], bb[ni2][kk], acc[(mh) * 4 + mi2][(nh) * 2 + ni2], 0, 0, 0); \
    __builtin_amdgcn_s_setprio(0);                                              \
  } while (0)

  // one barrier + one vmcnt per K-tile; all stages for T+1 target buf^1 (disjoint
  // from this body's reads). vmcnt(0) is ~free: issue-to-wait distance = full body.
#define TILE(T, P) do {                                                         \
    asm volatile("s_waitcnt vmcnt(0)" ::: "memory");                            \
    BARRIER;                                                                    \
    if ((T) + 1 < NT) {                                                         \
      STAGE_A((P) ^ 1, (T) + 1, 0); STAGE_B((P) ^ 1, (T) + 1, 0);               \
      STAGE_A((P) ^ 1, (T) + 1, 1); STAGE_B((P) ^ 1, (T) + 1, 1);               \
    }                                                                           \
    LOAD_A(P, 0); LOAD_B(b0, P, 0);                                             \
    MFMA_Q(b0, 0, 0);                                                           \
    LOAD_B(b1, P, 1);                                                           \
    MFMA_Q(b1, 0, 1);                                                           \
    LOAD_A(P, 1);                                                               \
    MFMA_Q(b1, 1, 1);                                                           \
    MFMA_Q(b0, 1, 0);                                                           \
  } while (0)

  // prologue: stage tile0 into buf0
  STAGE_A(0, 0, 0); STAGE_B(0, 0, 0); STAGE_A(0, 0, 1); STAGE_B(0, 0, 1);

  for (int T = 0; T < NT; T += 2) {
    TILE(T, 0);
    TILE(T + 1, 1);
  }

  // epilogue: C/D layout col = lane&15 (n), row = (lane>>4)*4 + r (m)
  const int rbase = lk * 4;
  const size_t gr0 = bmBase + wm * 128;
  const int gc0 = (int)bnBase + wn * 64;
#pragma unroll
  for (int mi = 0; mi < 8; ++mi) {
#pragma unroll
    for (int ni = 0; ni < 4; ++ni) {
      int gcol = gc0 + ni * 16 + lm;
      float bv = bias[gcol];
#pragma unroll
      for (int r = 0; r < 4; ++r) {
        size_t grow = gr0 + mi * 16 + rbase + r;
        float v = acc[mi][ni][r] + bv;
        if (EPI == 0) {
          ((u16*)Cout)[grow * ldc + gcol] = f2bf(v);
        } else {
          float gl = 0.5f * v * (1.0f + erff(v * 0.70710678118654752f));
          float y = gl + bf2f(residb[grow * 2048 + gcol]);
          ((float*)Cout)[grow * ldc + gcol] = y;
        }
      }
    }
  }
#undef STAGE_A
#undef STAGE_B
#undef LOAD_A
#undef LOAD_B
#undef MFMA_Q
#undef TILE
#undef BARRIER
}

// ---------------- fused: sim (MFMA) -> softmax -> retrieved (MFMA) ----------------
__global__ __launch_bounds__(256) void k_mid(const u16* __restrict__ h,
                                             const u16* __restrict__ pb,
                                             const u16* __restrict__ pbT,
                                             u16* __restrict__ comb) {
  __shared__ u16 attn_sm[4][16 * 32];
  const int tid = threadIdx.x;
  const int w = tid >> 6, lane = tid & 63;
  const int lm = lane & 15, lk = lane >> 4;
  const int row0 = blockIdx.x * 64 + w * 16;

  f32x4 zero = {0.f, 0.f, 0.f, 0.f};
  f32x4 acc0 = zero, acc1 = zero;
  float ss = 0.f;

  const u16* hrow = h + ((size_t)(row0 + lm) << 10) + lk * 8;
  const u16* pb0 = pb + (size_t)lm * DD + lk * 8;
  const u16* pb1 = pb + (size_t)(16 + lm) * DD + lk * 8;
#pragma unroll 4
  for (int k0 = 0; k0 < DD; k0 += 32) {
    bf16x8 af = *(const bf16x8*)(hrow + k0);
    bf16x8 b0 = *(const bf16x8*)(pb0 + k0);
    bf16x8 b1 = *(const bf16x8*)(pb1 + k0);
    acc0 = __builtin_amdgcn_mfma_f32_16x16x32_bf16(af, b0, acc0, 0, 0, 0);
    acc1 = __builtin_amdgcn_mfma_f32_16x16x32_bf16(af, b1, acc1, 0, 0, 0);
#pragma unroll
    for (int j = 0; j < 8; ++j) {
      float hv = bf2f((u16)af[j]);
      ss += hv * hv;
    }
  }
  ss += __shfl_xor(ss, 16);
  ss += __shfl_xor(ss, 32);
  float inv = 10.0f / fmaxf(sqrtf(ss), 1e-12f);

  float a0[4], a1[4];
#pragma unroll
  for (int r = 0; r < 4; ++r) {
    float invr = __shfl(inv, lk * 4 + r);
    float s0 = acc0[r] * invr;
    float s1 = acc1[r] * invr;
    float mr = fmaxf(s0, s1);
#pragma unroll
    for (int off = 1; off < 16; off <<= 1) mr = fmaxf(mr, __shfl_xor(mr, off));
    float e0 = expf(s0 - mr);
    float e1 = expf(s1 - mr);
    float sum = e0 + e1;
#pragma unroll
    for (int off = 1; off < 16; off <<= 1) sum += __shfl_xor(sum, off);
    float rs = 1.0f / sum;
    a0[r] = e0 * rs;
    a1[r] = e1 * rs;
  }

  u16* as = attn_sm[w];
#pragma unroll
  for (int r = 0; r < 4; ++r) {
    as[(lk * 4 + r) * 32 + lm] = f2bf(a0[r]);
    as[(lk * 4 + r) * 32 + 16 + lm] = f2bf(a1[r]);
  }
  __syncthreads();
  bf16x8 battn = *(const bf16x8*)(as + lm * 32 + lk * 8);

  u16* crow = comb + ((size_t)(row0 + lm) << 11) + DD;
#pragma unroll 4
  for (int d0 = 0; d0 < DD; d0 += 16) {
    bf16x8 ap = *(const bf16x8*)(pbT + (size_t)(d0 + lm) * PP + lk * 8);
    f32x4 rc = __builtin_amdgcn_mfma_f32_16x16x32_bf16(ap, battn, zero, 0, 0, 0);
    ushort4 o;
    o.x = f2bf(rc[0]); o.y = f2bf(rc[1]); o.z = f2bf(rc[2]); o.w = f2bf(rc[3]);
    *(ushort4*)(crow + d0 + lk * 4) = o;
  }
}

// ---------------- in-place LayerNorm over rows of 1024 ----------------
__global__ __launch_bounds__(256) void k_ln(float* __restrict__ io,
                                            const float* __restrict__ gamma,
                                            const float* __restrict__ beta) {
  __shared__ float sb[8];
  size_t row = blockIdx.x;
  float4* rp = (float4*)(io + (row << 10));
  int tid = threadIdx.x;
  float4 v = rp[tid];
  float s = v.x + v.y + v.z + v.w;
  float q = v.x * v.x + v.y * v.y + v.z * v.z + v.w * v.w;
#pragma unroll
  for (int off = 32; off; off >>= 1) { s += __shfl_xor(s, off); q += __shfl_xor(q, off); }
  if ((tid & 63) == 0) { sb[tid >> 6] = s; sb[4 + (tid >> 6)] = q; }
  __syncthreads();
  s = sb[0] + sb[1] + sb[2] + sb[3];
  q = sb[4] + sb[5] + sb[6] + sb[7];
  float mu = s * (1.f / 1024.f);
  float var = q * (1.f / 1024.f) - mu * mu;
  float rstd = rsqrtf(var + 1e-5f);
  float4 g = ((const float4*)gamma)[tid];
  float4 b = ((const float4*)beta)[tid];
  v.x = (v.x - mu) * rstd * g.x + b.x;
  v.y = (v.y - mu) * rstd * g.y + b.y;
  v.z = (v.z - mu) * rstd * g.z + b.z;
  v.w = (v.w - mu) * rstd * g.w + b.w;
  rp[tid] = v;
}

extern "C" void kernel_launch(void* const* d_in, const int* in_sizes, int n_in,
                              void* d_out, int out_size, void* d_ws, size_t ws_size,
                              hipStream_t stream) {
  const float* x      = (const float*)d_in[0];
  const float* Wi     = (const float*)d_in[1];
  const float* bi     = (const float*)d_in[2];
  const float* Wo     = (const float*)d_in[3];
  const float* bo     = (const float*)d_in[4];
  const float* gamma  = (const float*)d_in[5];
  const float* beta   = (const float*)d_in[6];
  const float* protos = (const float*)d_in[7];
  const int Brows = in_sizes[0] / DD;  // 65536

  u16* comb = (u16*)d_ws;                        // [B, 2048] bf16
  u16* WiB  = comb + (size_t)Brows * 2048;       // [1024, 1024]
  u16* WoB  = WiB + (size_t)1024 * 1024;         // [1024, 2048]
  u16* pb   = WoB + (size_t)1024 * 2048;         // [32, 1024] normalized
  u16* pbT  = pb + (size_t)PP * DD;              // [1024, 32] raw transposed
  u16* hbuf = (u16*)d_out;                       // h bf16 lives in d_out storage

  k_convert_x<<<4096, 256, 0, stream>>>(x, comb, Brows * 256);
  k_convert<<<1024, 256, 0, stream>>>(Wi, WiB, 1024 * 1024 / 4);
  k_convert<<<2048, 256, 0, stream>>>(Wo, WoB, 1024 * 2048 / 4);
  k_proto_prep<<<PP, 256, 0, stream>>>(protos, pb);
  k_protoT<<<(DD * PP + 255) / 256, 256, 0, stream>>>(protos, pbT);

  const int nbn = 1024 / 256;                    // 4 col-blocks
  const int nwg = nbn * (Brows / 256);           // 1024 blocks

  // h = x @ Wi^T + bi
  k_gemm8<0><<<nwg, 512, 0, stream>>>(comb, 2048, WiB, bi, nullptr,
                                      (void*)hbuf, DD, DD, nbn);
  // fused sim -> softmax -> retrieved into combined right half
  k_mid<<<Brows / 64, 256, 0, stream>>>(hbuf, pb, pbT, comb);
  // y = gelu(combined @ Wo^T + bo) + bf16(x)  -> d_out (f32)
  k_gemm8<1><<<nwg, 512, 0, stream>>>(comb, 2048, WoB, bo, comb,
                                      d_out, DD, 2 * DD, nbn);
  // in-place LayerNorm
  k_ln<<<Brows, 256, 0, stream>>>((float*)d_out, gamma, beta);
}